// Round 15
// baseline (222.559 us; speedup 1.0000x reference)
//
#include <hip/hip_runtime.h>
#include <hip/hip_bf16.h>

typedef unsigned short u16;
typedef short bf16x8 __attribute__((ext_vector_type(8)));
typedef float f32x4 __attribute__((ext_vector_type(4)));
typedef u16 us8 __attribute__((ext_vector_type(8)));
typedef u16 us4 __attribute__((ext_vector_type(4)));

#define NEGV -10000.0f

static __device__ __forceinline__ u16 f2bf(float f) {
    __hip_bfloat16 h = __float2bfloat16(f);
    return __builtin_bit_cast(u16, h);
}

static __device__ __forceinline__ float bf2f(u16 v) {
    unsigned int u = ((unsigned int)v) << 16;
    return __builtin_bit_cast(float, u);
}

#define GLOAD_LDS16(g, l)                                                      \
    __builtin_amdgcn_global_load_lds(                                          \
        (const __attribute__((address_space(1))) void*)(g),                    \
        (__attribute__((address_space(3))) void*)(l), 16, 0, 0)

#define MFMA16(a, b, c) __builtin_amdgcn_mfma_f32_16x16x32_bf16(a, b, c, 0, 0, 0)

// ---------------- fp32 -> bf16 convert ----------------
__global__ __launch_bounds__(256) void cvt_bf16(const float* __restrict__ src,
                                                u16* __restrict__ dst, int n4) {
    int i = blockIdx.x * 256 + threadIdx.x;
    if (i < n4) {
        float4 v = ((const float4*)src)[i];
        ushort4 o;
        o.x = f2bf(v.x); o.y = f2bf(v.y); o.z = f2bf(v.z); o.w = f2bf(v.w);
        ((ushort4*)dst)[i] = o;
    }
}

// ---- GEMM: out_bf16 = A @ B^T + bias. Tile 64x128, grid (8,64) ----
__global__ __launch_bounds__(256) void gemm_q_kernel(
    const u16* __restrict__ A, const u16* __restrict__ Bw,
    const float* __restrict__ bias, u16* __restrict__ out) {
    const int K = 1024;
    __shared__ __align__(16) u16 Al[64 * 32];
    __shared__ __align__(16) u16 Bl[128 * 32];
    int t = threadIdx.x, w = t >> 6, l = t & 63;
    int wr = w >> 1, wc = w & 1;
    int row0 = blockIdx.y * 64, col0 = blockIdx.x * 128;
    int ar = t >> 2, ac = (t & 3) * 8;
    f32x4 acc[2][4] = {};
    for (int k0 = 0; k0 < K; k0 += 32) {
        __syncthreads();
        GLOAD_LDS16(A + (size_t)(row0 + ar) * K + k0 + ac, &Al[ar * 32 + ac]);
        GLOAD_LDS16(Bw + (size_t)(col0 + ar) * K + k0 + ac, &Bl[ar * 32 + ac]);
        GLOAD_LDS16(Bw + (size_t)(col0 + 64 + ar) * K + k0 + ac, &Bl[(64 + ar) * 32 + ac]);
        __syncthreads();
        bf16x8 a[2], b[4];
#pragma unroll
        for (int m = 0; m < 2; m++)
            a[m] = *(const bf16x8*)&Al[(wr * 32 + m * 16 + (l & 15)) * 32 + ((l >> 4) * 8)];
#pragma unroll
        for (int n = 0; n < 4; n++)
            b[n] = *(const bf16x8*)&Bl[(wc * 64 + n * 16 + (l & 15)) * 32 + ((l >> 4) * 8)];
#pragma unroll
        for (int m = 0; m < 2; m++)
#pragma unroll
            for (int n = 0; n < 4; n++)
                acc[m][n] = MFMA16(a[m], b[n], acc[m][n]);
    }
    int cr = (l >> 4) * 4, cc = l & 15;
#pragma unroll
    for (int m = 0; m < 2; m++)
#pragma unroll
        for (int n = 0; n < 4; n++) {
            int col = col0 + wc * 64 + n * 16 + cc;
            float bv = bias[col];
#pragma unroll
            for (int r = 0; r < 4; r++) {
                int row = row0 + wr * 32 + m * 16 + cr + r;
                out[(size_t)row * 1024 + col] = f2bf(acc[m][n][r] + bv);
            }
        }
}

// ---- GEMM: x_f32 = A @ B^T + bias + resid. Same 64x128 tiling. ----
__global__ __launch_bounds__(256) void gemm_o_kernel(
    const u16* __restrict__ A, const u16* __restrict__ Bw,
    const float* __restrict__ bias, const float* __restrict__ resid,
    float* __restrict__ out) {
    const int K = 1024;
    __shared__ __align__(16) u16 Al[64 * 32];
    __shared__ __align__(16) u16 Bl[128 * 32];
    int t = threadIdx.x, w = t >> 6, l = t & 63;
    int wr = w >> 1, wc = w & 1;
    int row0 = blockIdx.y * 64, col0 = blockIdx.x * 128;
    int ar = t >> 2, ac = (t & 3) * 8;
    f32x4 acc[2][4] = {};
    for (int k0 = 0; k0 < K; k0 += 32) {
        __syncthreads();
        GLOAD_LDS16(A + (size_t)(row0 + ar) * K + k0 + ac, &Al[ar * 32 + ac]);
        GLOAD_LDS16(Bw + (size_t)(col0 + ar) * K + k0 + ac, &Bl[ar * 32 + ac]);
        GLOAD_LDS16(Bw + (size_t)(col0 + 64 + ar) * K + k0 + ac, &Bl[(64 + ar) * 32 + ac]);
        __syncthreads();
        bf16x8 a[2], b[4];
#pragma unroll
        for (int m = 0; m < 2; m++)
            a[m] = *(const bf16x8*)&Al[(wr * 32 + m * 16 + (l & 15)) * 32 + ((l >> 4) * 8)];
#pragma unroll
        for (int n = 0; n < 4; n++)
            b[n] = *(const bf16x8*)&Bl[(wc * 64 + n * 16 + (l & 15)) * 32 + ((l >> 4) * 8)];
#pragma unroll
        for (int m = 0; m < 2; m++)
#pragma unroll
            for (int n = 0; n < 4; n++)
                acc[m][n] = MFMA16(a[m], b[n], acc[m][n]);
    }
    int cr = (l >> 4) * 4, cc = l & 15;
#pragma unroll
    for (int m = 0; m < 2; m++)
#pragma unroll
        for (int n = 0; n < 4; n++) {
            int col = col0 + wc * 64 + n * 16 + cc;
            float bv = bias[col];
#pragma unroll
            for (int r = 0; r < 4; r++) {
                int row = row0 + wr * 32 + m * 16 + cr + r;
                out[(size_t)row * 1024 + col] =
                    acc[m][n][r] + bv + resid[(size_t)row * 1024 + col];
            }
        }
}

// ---------------- per-head transpose: Qt[b,h,dh,s] = Q[b,s,h*64+dh] ----------
__global__ __launch_bounds__(256) void transpose_q(const u16* __restrict__ Q,
                                                   u16* __restrict__ Qt) {
    __shared__ u16 T[64][72];
    int t = threadIdx.x;
    int s0 = blockIdx.x * 64, h = blockIdx.y, b = blockIdx.z;
    int c8 = (t & 7) * 8;
#pragma unroll
    for (int half = 0; half < 2; half++) {
        int r = (t >> 3) + half * 32;
        us8 v = *(const us8*)(Q + (size_t)(b * 2048 + s0 + r) * 1024 + h * 64 + c8);
#pragma unroll
        for (int j = 0; j < 8; j++) T[r][c8 + j] = v[j];
    }
    __syncthreads();
    int s8 = (t & 7) * 8;
#pragma unroll
    for (int half = 0; half < 2; half++) {
        int d = (t >> 3) + half * 32;
        us8 o;
#pragma unroll
        for (int j = 0; j < 8; j++) o[j] = T[s8 + j][d];
        *(us8*)(Qt + (size_t)((b * 16 + h) * 64 + d) * 2048 + s0 + s8) = o;
    }
}

// ---------------- fused attention (R15): Pl-only store path ----------------
// R15 change (single mechanism): drop the f32 P LDS tile. probs stores read
// the bf16 Pl tile (already needed for the PV fragment), convert bf16->f32
// in-register, and store full-128B-line NT f32x4 runs (same line pattern as
// R11/R14's best store path). Precision: probs round-trips bf16 (err <=4e-3,
// 5x inside the ~0.02 threshold; PV already consumed the same bf16 values).
// LDS 48->40KB => 4 blocks/CU resident (grid 1024 = exactly 4/CU), raising
// the fraction of wall time during which some resident block is in its
// write phase (R14 model: writes flow ~2/3 of wall at 3 blocks/CU).
__global__ __launch_bounds__(256, 4) void attn_kernel(
    const u16* __restrict__ Q,    // [B,S,D] bf16
    const u16* __restrict__ Qt,   // [B,H,DH,S] bf16 (V^T per head)
    const float* __restrict__ mask,
    float* __restrict__ probs,    // [B,H,S,S] fp32
    u16* __restrict__ ctx) {      // [B,S,D] bf16
    const int S = 2048, D = 1024;
    __shared__ __align__(16) u16 Kl[2][4096];   // 16KB
    __shared__ __align__(16) u16 Vl[2][4096];   // 16KB
    __shared__ __align__(16) char Pl[4][2048];  // 8KB (bf16 P)
    int id = blockIdx.x;
    int wgid = (id & 7) * 128 + (id >> 3);      // XCD swizzle (1024 % 8 == 0)
    int qt = 31 - (wgid & 31);                  // qt descending in launch order
    int h = (wgid >> 5) & 15, b = wgid >> 9;
    int t = threadIdx.x, w = t >> 6, l = t & 63;
    int g = l >> 4, q16 = l & 15;
    size_t pb = ((size_t)(b * 16 + h)) * S * S;
    const u16* Qh = Q + (size_t)b * S * D + h * 64;        // row stride D
    const u16* Vh = Qt + ((size_t)(b * 16 + h) * 64) * S;  // row stride S
    const float* mrow = mask + b * S;

    // staging: thread t covers LDS byte slots t*16 and 4096+t*16.
    // slot byte s holds global (row = s>>7, chunk = ((s>>4)&7) ^ (row&7)).
    int krow0 = t >> 3, kc0 = (((t & 7) ^ (krow0 & 7)) * 8);
    int krow1 = (t >> 3) + 32, kc1 = (((t & 7) ^ (krow1 & 7)) * 8);

#define STAGE_K(buf, kt)                                                        \
    do {                                                                        \
        GLOAD_LDS16(Qh + (size_t)((kt) * 64 + krow0) * D + kc0, &Kl[buf][t * 8]);\
        GLOAD_LDS16(Qh + (size_t)((kt) * 64 + krow1) * D + kc1,                  \
                    &Kl[buf][2048 + t * 8]);                                     \
    } while (0)
#define STAGE_V(buf, kt)                                                        \
    do {                                                                        \
        GLOAD_LDS16(Vh + (size_t)krow0 * S + (kt) * 64 + kc0, &Vl[buf][t * 8]);  \
        GLOAD_LDS16(Vh + (size_t)krow1 * S + (kt) * 64 + kc1,                    \
                    &Vl[buf][2048 + t * 8]);                                     \
    } while (0)

    int swz = (q16 & 7) << 4;
    int qrow = qt * 64 + w * 16 + q16;
    const u16* qp = Qh + (size_t)qrow * D;
    bf16x8 bq0 = *(const bf16x8*)(qp + g * 8);
    bf16x8 bq1 = *(const bf16x8*)(qp + 32 + g * 8);

    // ---- pass 1: row sums of exp(s) ----
    float lsum = 0.f;
    STAGE_K(0, 0);
    __syncthreads();
    for (int kt = 0; kt <= qt; kt++) {
        int cur = kt & 1;
        if (kt < qt) STAGE_K(cur ^ 1, kt + 1);
#pragma unroll
        for (int n = 0; n < 4; n++) {
            int rowa = n * 16 + q16;
            int ba0 = (rowa * 128 + g * 16) ^ swz;
            int ba1 = (rowa * 128 + 64 + g * 16) ^ swz;
            bf16x8 a0 = *(const bf16x8*)((const char*)Kl[cur] + ba0);
            bf16x8 a1 = *(const bf16x8*)((const char*)Kl[cur] + ba1);
            f32x4 s = {};
            s = MFMA16(a0, bq0, s);
            s = MFMA16(a1, bq1, s);
            int kg = kt * 64 + n * 16 + g * 4;
            float4 mv = *(const float4*)&mrow[kg];
            lsum += (kg + 0 <= qrow) ? __expf(s[0] * 0.03125f + (1.0f - mv.x) * NEGV) : 0.f;
            lsum += (kg + 1 <= qrow) ? __expf(s[1] * 0.03125f + (1.0f - mv.y) * NEGV) : 0.f;
            lsum += (kg + 2 <= qrow) ? __expf(s[2] * 0.03125f + (1.0f - mv.z) * NEGV) : 0.f;
            lsum += (kg + 3 <= qrow) ? __expf(s[3] * 0.03125f + (1.0f - mv.w) * NEGV) : 0.f;
        }
        __syncthreads();
    }
    lsum += __shfl_xor(lsum, 16);
    lsum += __shfl_xor(lsum, 32);
    float rl = 1.0f / lsum;

    // ---- pass 2: probs from Pl (bf16->f32, full-line NT) + PV ----
    f32x4 cacc[4] = {};
    STAGE_K(0, 0);
    STAGE_V(0, 0);
    __syncthreads();
    for (int kt = 0; kt <= qt; kt++) {
        int cur = kt & 1;
        if (kt < qt) { STAGE_K(cur ^ 1, kt + 1); STAGE_V(cur ^ 1, kt + 1); }
#pragma unroll
        for (int n = 0; n < 4; n++) {
            int rowa = n * 16 + q16;
            int ba0 = (rowa * 128 + g * 16) ^ swz;
            int ba1 = (rowa * 128 + 64 + g * 16) ^ swz;
            bf16x8 a0 = *(const bf16x8*)((const char*)Kl[cur] + ba0);
            bf16x8 a1 = *(const bf16x8*)((const char*)Kl[cur] + ba1);
            f32x4 s = {};
            s = MFMA16(a0, bq0, s);
            s = MFMA16(a1, bq1, s);
            int kg = kt * 64 + n * 16 + g * 4;
            float4 mv = *(const float4*)&mrow[kg];
            float pv[4];
            pv[0] = (kg + 0 <= qrow) ? __expf(s[0] * 0.03125f + (1.0f - mv.x) * NEGV) * rl : 0.f;
            pv[1] = (kg + 1 <= qrow) ? __expf(s[1] * 0.03125f + (1.0f - mv.y) * NEGV) * rl : 0.f;
            pv[2] = (kg + 2 <= qrow) ? __expf(s[2] * 0.03125f + (1.0f - mv.z) * NEGV) * rl : 0.f;
            pv[3] = (kg + 3 <= qrow) ? __expf(s[3] * 0.03125f + (1.0f - mv.w) * NEGV) * rl : 0.f;
            us4 pk;
#pragma unroll
            for (int r = 0; r < 4; r++) pk[r] = f2bf(pv[r]);
            int wb = (q16 * 128 + n * 32 + g * 8) ^ swz;
            *(us4*)(&Pl[w][wb]) = pk;
        }
        asm volatile("s_waitcnt lgkmcnt(0)" ::: "memory");
        __builtin_amdgcn_sched_barrier(0);
        bf16x8 pa0, pa1;
        {
            int rb0 = (q16 * 128 + g * 16) ^ swz;
            int rb1 = (q16 * 128 + 64 + g * 16) ^ swz;
            pa0 = *(const bf16x8*)(&Pl[w][rb0]);
            pa1 = *(const bf16x8*)(&Pl[w][rb1]);
        }
        // probs store from Pl: per j, 16 lanes cover one row's 64 k values
        // as 256B contiguous f32 (full 128B lines), NT. 4 instrs/lane/iter.
#pragma unroll
        for (int j = 0; j < 4; j++) {
            int row = (l >> 4) + j * 4;
            int rb = (row * 128 + (l & 15) * 8) ^ ((row & 7) << 4);
            us4 pk = *(const us4*)(&Pl[w][rb]);
            f32x4 pvv;
#pragma unroll
            for (int r = 0; r < 4; r++) pvv[r] = bf2f(pk[r]);
            __builtin_nontemporal_store(
                pvv, (f32x4*)&probs[pb + (size_t)(qt * 64 + w * 16 + row) * S +
                                    kt * 64 + (l & 15) * 4]);
        }
#pragma unroll
        for (int n = 0; n < 4; n++) {
            int rowv = n * 16 + q16;
            int bv0 = (rowv * 128 + g * 16) ^ swz;
            int bv1 = (rowv * 128 + 64 + g * 16) ^ swz;
            bf16x8 v0 = *(const bf16x8*)((const char*)Vl[cur] + bv0);
            bf16x8 v1 = *(const bf16x8*)((const char*)Vl[cur] + bv1);
            cacc[n] = MFMA16(pa0, v0, cacc[n]);
            cacc[n] = MFMA16(pa1, v1, cacc[n]);
        }
        // vmcnt(4): the 4 NT probs stores (newest) may stay in flight;
        // everything older (stage loads, mask loads) has retired.
        asm volatile("s_waitcnt vmcnt(4)" ::: "memory");
        __builtin_amdgcn_s_barrier();
        __builtin_amdgcn_sched_barrier(0);
    }

    // ---- ctx store ----
    u16* cp = ctx + ((size_t)b * S + qt * 64 + w * 16) * D + h * 64;
#pragma unroll
    for (int n = 0; n < 4; n++)
#pragma unroll
        for (int r = 0; r < 4; r++)
            cp[(size_t)(g * 4 + r) * D + n * 16 + q16] = f2bf(cacc[n][r]);

    // ---- zero-fill future-k tiles for this qt (nt, full lines) ----
    for (int kt = qt + 1; kt < 32; kt++) {
        f32x4 z = {0.f, 0.f, 0.f, 0.f};
#pragma unroll
        for (int j = 0; j < 4; j++) {
            int slot = t + j * 256;
            int rr = slot >> 4, c4 = (slot & 15) * 4;
            __builtin_nontemporal_store(
                z, (f32x4*)&probs[pb + (size_t)(qt * 64 + rr) * S + kt * 64 + c4]);
        }
    }
#undef STAGE_K
#undef STAGE_V
}

// ---------------- LayerNorm (block per row) ----------------
__global__ __launch_bounds__(256) void ln_kernel(const float* __restrict__ x,
                                                 const float* __restrict__ gamma,
                                                 const float* __restrict__ beta,
                                                 float* __restrict__ out) {
    int row = blockIdx.x, t = threadIdx.x, w = t >> 6, l = t & 63;
    __shared__ float red[8];
    float4 v = ((const float4*)(x + (size_t)row * 1024))[t];
    float s1 = v.x + v.y + v.z + v.w;
    float s2 = v.x * v.x + v.y * v.y + v.z * v.z + v.w * v.w;
#pragma unroll
    for (int mk = 1; mk < 64; mk <<= 1) {
        s1 += __shfl_xor(s1, mk);
        s2 += __shfl_xor(s2, mk);
    }
    if (l == 0) { red[w] = s1; red[4 + w] = s2; }
    __syncthreads();
    float S1 = red[0] + red[1] + red[2] + red[3];
    float S2 = red[4] + red[5] + red[6] + red[7];
    float mu = S1 * (1.0f / 1024.0f);
    float var = S2 * (1.0f / 1024.0f) - mu * mu;
    float inv = rsqrtf(var + 1e-12f);
    float4 g = ((const float4*)gamma)[t];
    float4 bt = ((const float4*)beta)[t];
    float4 o;
    o.x = g.x * (v.x - mu) * inv + bt.x;
    o.y = g.y * (v.y - mu) * inv + bt.y;
    o.z = g.z * (v.z - mu) * inv + bt.z;
    o.w = g.w * (v.w - mu) * inv + bt.w;
    ((float4*)(out + (size_t)row * 1024))[t] = o;
}

extern "C" void kernel_launch(void* const* d_in, const int* in_sizes, int n_in,
                              void* d_out, int out_size, void* d_ws, size_t ws_size,
                              hipStream_t stream) {
    const float* emb   = (const float*)d_in[0];
    const float* mask  = (const float*)d_in[1];
    const float* Wq    = (const float*)d_in[2];
    const float* bq    = (const float*)d_in[3];
    const float* Wo    = (const float*)d_in[8];
    const float* bo    = (const float*)d_in[9];
    const float* gamma = (const float*)d_in[10];
    const float* beta  = (const float*)d_in[11];
    float* out_ln = (float*)d_out;
    float* probs  = (float*)d_out + (size_t)2 * 2048 * 1024;

    char* ws = (char*)d_ws;
    u16* emb_bf = (u16*)ws; ws += (size_t)8388608;
    u16* Wq_bf  = (u16*)ws; ws += (size_t)2097152;
    u16* Wo_bf  = (u16*)ws; ws += (size_t)2097152;
    u16* Qb     = (u16*)ws; ws += (size_t)8388608;
    u16* Qtb    = (u16*)ws; ws += (size_t)8388608;
    u16* ctxb   = (u16*)ws; ws += (size_t)8388608;
    float* xf   = (float*)ws;

    cvt_bf16<<<4096, 256, 0, stream>>>(emb, emb_bf, 1048576);
    cvt_bf16<<<1024, 256, 0, stream>>>(Wq, Wq_bf, 262144);
    cvt_bf16<<<1024, 256, 0, stream>>>(Wo, Wo_bf, 262144);
    gemm_q_kernel<<<dim3(8, 64), 256, 0, stream>>>(emb_bf, Wq_bf, bq, Qb);
    transpose_q<<<dim3(32, 16, 2), 256, 0, stream>>>(Qb, Qtb);
    attn_kernel<<<1024, 256, 0, stream>>>(Qb, Qtb, mask, probs, ctxb);
    gemm_o_kernel<<<dim3(8, 64), 256, 0, stream>>>(ctxb, Wo_bf, bo, emb, xf);
    ln_kernel<<<4096, 256, 0, stream>>>(xf, gamma, beta, out_ln);
}

// Round 16
// 199.792 us; speedup vs baseline: 1.1139x; 1.1139x over previous
//
#include <hip/hip_runtime.h>
#include <hip/hip_bf16.h>

typedef unsigned short u16;
typedef short bf16x8 __attribute__((ext_vector_type(8)));
typedef float f32x4 __attribute__((ext_vector_type(4)));
typedef u16 us8 __attribute__((ext_vector_type(8)));
typedef u16 us4 __attribute__((ext_vector_type(4)));

#define NEGV -10000.0f

static __device__ __forceinline__ u16 f2bf(float f) {
    __hip_bfloat16 h = __float2bfloat16(f);
    return __builtin_bit_cast(u16, h);
}

#define GLOAD_LDS16(g, l)                                                      \
    __builtin_amdgcn_global_load_lds(                                          \
        (const __attribute__((address_space(1))) void*)(g),                    \
        (__attribute__((address_space(3))) void*)(l), 16, 0, 0)

#define MFMA16(a, b, c) __builtin_amdgcn_mfma_f32_16x16x32_bf16(a, b, c, 0, 0, 0)

// ---------------- fp32 -> bf16 convert ----------------
__global__ __launch_bounds__(256) void cvt_bf16(const float* __restrict__ src,
                                                u16* __restrict__ dst, int n4) {
    int i = blockIdx.x * 256 + threadIdx.x;
    if (i < n4) {
        float4 v = ((const float4*)src)[i];
        ushort4 o;
        o.x = f2bf(v.x); o.y = f2bf(v.y); o.z = f2bf(v.z); o.w = f2bf(v.w);
        ((ushort4*)dst)[i] = o;
    }
}

// ---- GEMM: out_bf16 = A @ B^T + bias. Tile 64x128, BK=64, XOR-swizzled LDS.
// R16: old layout ([row][32] u16, 64B row stride) had lanes 0-15 of each
// fragment read hitting 2 bank groups = 8-way ds_read_b128 conflict (~2.9x).
// New: [row][64] u16 rows, 16B chunk c stored at position c^(row&7) (global
// source inverse-permuted, LDS dest linear per rule #21); fragment reads at
// chunk (kk*4+g)^(row&7) spread all 32 banks (2-way = free). BK=64 also
// halves barriers (2 per 64-K, 16 MFMA between).
__global__ __launch_bounds__(256) void gemm_q_kernel(
    const u16* __restrict__ A, const u16* __restrict__ Bw,
    const float* __restrict__ bias, u16* __restrict__ out) {
    const int K = 1024;
    __shared__ __align__(16) u16 Al[64 * 64];    // 8KB
    __shared__ __align__(16) u16 Bl[128 * 64];   // 16KB
    int t = threadIdx.x, w = t >> 6, l = t & 63;
    int wr = w >> 1, wc = w & 1;
    int row0 = blockIdx.y * 64, col0 = blockIdx.x * 128;
    int srow = t >> 3, schunk = t & 7;
    f32x4 acc[2][4] = {};
    for (int k0 = 0; k0 < K; k0 += 64) {
        __syncthreads();
        {
            int r0 = srow, c0 = (schunk ^ (r0 & 7)) * 8;
            GLOAD_LDS16(A + (size_t)(row0 + r0) * K + k0 + c0, &Al[t * 8]);
            int r1 = srow + 32, c1 = (schunk ^ (r1 & 7)) * 8;
            GLOAD_LDS16(A + (size_t)(row0 + r1) * K + k0 + c1, &Al[2048 + t * 8]);
        }
#pragma unroll
        for (int j = 0; j < 4; j++) {
            int r = srow + j * 32, c = (schunk ^ (r & 7)) * 8;
            GLOAD_LDS16(Bw + (size_t)(col0 + r) * K + k0 + c, &Bl[j * 2048 + t * 8]);
        }
        __syncthreads();
#pragma unroll
        for (int kk = 0; kk < 2; kk++) {
            bf16x8 a[2], b[4];
#pragma unroll
            for (int m = 0; m < 2; m++) {
                int row = wr * 32 + m * 16 + (l & 15);
                int ch = (kk * 4 + (l >> 4)) ^ (row & 7);
                a[m] = *(const bf16x8*)&Al[row * 64 + ch * 8];
            }
#pragma unroll
            for (int n = 0; n < 4; n++) {
                int row = wc * 64 + n * 16 + (l & 15);
                int ch = (kk * 4 + (l >> 4)) ^ (row & 7);
                b[n] = *(const bf16x8*)&Bl[row * 64 + ch * 8];
            }
#pragma unroll
            for (int m = 0; m < 2; m++)
#pragma unroll
                for (int n = 0; n < 4; n++)
                    acc[m][n] = MFMA16(a[m], b[n], acc[m][n]);
        }
    }
    int cr = (l >> 4) * 4, cc = l & 15;
#pragma unroll
    for (int m = 0; m < 2; m++)
#pragma unroll
        for (int n = 0; n < 4; n++) {
            int col = col0 + wc * 64 + n * 16 + cc;
            float bv = bias[col];
#pragma unroll
            for (int r = 0; r < 4; r++) {
                int row = row0 + wr * 32 + m * 16 + cr + r;
                out[(size_t)row * 1024 + col] = f2bf(acc[m][n][r] + bv);
            }
        }
}

// ---- GEMM: x_f32 = A @ B^T + bias + resid. Same BK=64 swizzled tiling. ----
__global__ __launch_bounds__(256) void gemm_o_kernel(
    const u16* __restrict__ A, const u16* __restrict__ Bw,
    const float* __restrict__ bias, const float* __restrict__ resid,
    float* __restrict__ out) {
    const int K = 1024;
    __shared__ __align__(16) u16 Al[64 * 64];
    __shared__ __align__(16) u16 Bl[128 * 64];
    int t = threadIdx.x, w = t >> 6, l = t & 63;
    int wr = w >> 1, wc = w & 1;
    int row0 = blockIdx.y * 64, col0 = blockIdx.x * 128;
    int srow = t >> 3, schunk = t & 7;
    f32x4 acc[2][4] = {};
    for (int k0 = 0; k0 < K; k0 += 64) {
        __syncthreads();
        {
            int r0 = srow, c0 = (schunk ^ (r0 & 7)) * 8;
            GLOAD_LDS16(A + (size_t)(row0 + r0) * K + k0 + c0, &Al[t * 8]);
            int r1 = srow + 32, c1 = (schunk ^ (r1 & 7)) * 8;
            GLOAD_LDS16(A + (size_t)(row0 + r1) * K + k0 + c1, &Al[2048 + t * 8]);
        }
#pragma unroll
        for (int j = 0; j < 4; j++) {
            int r = srow + j * 32, c = (schunk ^ (r & 7)) * 8;
            GLOAD_LDS16(Bw + (size_t)(col0 + r) * K + k0 + c, &Bl[j * 2048 + t * 8]);
        }
        __syncthreads();
#pragma unroll
        for (int kk = 0; kk < 2; kk++) {
            bf16x8 a[2], b[4];
#pragma unroll
            for (int m = 0; m < 2; m++) {
                int row = wr * 32 + m * 16 + (l & 15);
                int ch = (kk * 4 + (l >> 4)) ^ (row & 7);
                a[m] = *(const bf16x8*)&Al[row * 64 + ch * 8];
            }
#pragma unroll
            for (int n = 0; n < 4; n++) {
                int row = wc * 64 + n * 16 + (l & 15);
                int ch = (kk * 4 + (l >> 4)) ^ (row & 7);
                b[n] = *(const bf16x8*)&Bl[row * 64 + ch * 8];
            }
#pragma unroll
            for (int m = 0; m < 2; m++)
#pragma unroll
                for (int n = 0; n < 4; n++)
                    acc[m][n] = MFMA16(a[m], b[n], acc[m][n]);
        }
    }
    int cr = (l >> 4) * 4, cc = l & 15;
#pragma unroll
    for (int m = 0; m < 2; m++)
#pragma unroll
        for (int n = 0; n < 4; n++) {
            int col = col0 + wc * 64 + n * 16 + cc;
            float bv = bias[col];
#pragma unroll
            for (int r = 0; r < 4; r++) {
                int row = row0 + wr * 32 + m * 16 + cr + r;
                out[(size_t)row * 1024 + col] =
                    acc[m][n][r] + bv + resid[(size_t)row * 1024 + col];
            }
        }
}

// ---------------- per-head transpose: Qt[b,h,dh,s] = Q[b,s,h*64+dh] ----------
__global__ __launch_bounds__(256) void transpose_q(const u16* __restrict__ Q,
                                                   u16* __restrict__ Qt) {
    __shared__ u16 T[64][72];
    int t = threadIdx.x;
    int s0 = blockIdx.x * 64, h = blockIdx.y, b = blockIdx.z;
    int c8 = (t & 7) * 8;
#pragma unroll
    for (int half = 0; half < 2; half++) {
        int r = (t >> 3) + half * 32;
        us8 v = *(const us8*)(Q + (size_t)(b * 2048 + s0 + r) * 1024 + h * 64 + c8);
#pragma unroll
        for (int j = 0; j < 8; j++) T[r][c8 + j] = v[j];
    }
    __syncthreads();
    int s8 = (t & 7) * 8;
#pragma unroll
    for (int half = 0; half < 2; half++) {
        int d = (t >> 3) + half * 32;
        us8 o;
#pragma unroll
        for (int j = 0; j < 8; j++) o[j] = T[s8 + j][d];
        *(us8*)(Qt + (size_t)((b * 16 + h) * 64 + d) * 2048 + s0 + s8) = o;
    }
}

// ---------------- fused attention: R14 config (best measured, 204.5us) -----
// Store path: full-128B-line NT flush via f32 half-tile Pfh. LDS 48KB,
// launch_bounds(256,3), grid 1024 (one qt/block, qt descending).
__global__ __launch_bounds__(256, 3) void attn_kernel(
    const u16* __restrict__ Q,    // [B,S,D] bf16
    const u16* __restrict__ Qt,   // [B,H,DH,S] bf16 (V^T per head)
    const float* __restrict__ mask,
    float* __restrict__ probs,    // [B,H,S,S] fp32
    u16* __restrict__ ctx) {      // [B,S,D] bf16
    const int S = 2048, D = 1024;
    __shared__ __align__(16) u16 Kl[2][4096];    // 16KB
    __shared__ __align__(16) u16 Vl[2][4096];    // 16KB
    __shared__ __align__(16) char Pl[4][2048];   // 8KB (bf16 P for PV MFMA)
    __shared__ __align__(16) float Pfh[4][512];  // 8KB (f32 P half, 128B/row)
    int id = blockIdx.x;
    int wgid = (id & 7) * 128 + (id >> 3);      // XCD swizzle (1024 % 8 == 0)
    int qt = 31 - (wgid & 31);                  // qt descending in launch order
    int h = (wgid >> 5) & 15, b = wgid >> 9;
    int t = threadIdx.x, w = t >> 6, l = t & 63;
    int g = l >> 4, q16 = l & 15;
    size_t pb = ((size_t)(b * 16 + h)) * S * S;
    const u16* Qh = Q + (size_t)b * S * D + h * 64;        // row stride D
    const u16* Vh = Qt + ((size_t)(b * 16 + h) * 64) * S;  // row stride S
    const float* mrow = mask + b * S;

    int krow0 = t >> 3, kc0 = (((t & 7) ^ (krow0 & 7)) * 8);
    int krow1 = (t >> 3) + 32, kc1 = (((t & 7) ^ (krow1 & 7)) * 8);

#define STAGE_K(buf, kt)                                                        \
    do {                                                                        \
        GLOAD_LDS16(Qh + (size_t)((kt) * 64 + krow0) * D + kc0, &Kl[buf][t * 8]);\
        GLOAD_LDS16(Qh + (size_t)((kt) * 64 + krow1) * D + kc1,                  \
                    &Kl[buf][2048 + t * 8]);                                     \
    } while (0)
#define STAGE_V(buf, kt)                                                        \
    do {                                                                        \
        GLOAD_LDS16(Vh + (size_t)krow0 * S + (kt) * 64 + kc0, &Vl[buf][t * 8]);  \
        GLOAD_LDS16(Vh + (size_t)krow1 * S + (kt) * 64 + kc1,                    \
                    &Vl[buf][2048 + t * 8]);                                     \
    } while (0)

    int swz = (q16 & 7) << 4;
    int qrow = qt * 64 + w * 16 + q16;
    const u16* qp = Qh + (size_t)qrow * D;
    bf16x8 bq0 = *(const bf16x8*)(qp + g * 8);
    bf16x8 bq1 = *(const bf16x8*)(qp + 32 + g * 8);

    // ---- pass 1: row sums of exp(s) ----
    float lsum = 0.f;
    STAGE_K(0, 0);
    __syncthreads();
    for (int kt = 0; kt <= qt; kt++) {
        int cur = kt & 1;
        if (kt < qt) STAGE_K(cur ^ 1, kt + 1);
#pragma unroll
        for (int n = 0; n < 4; n++) {
            int rowa = n * 16 + q16;
            int ba0 = (rowa * 128 + g * 16) ^ swz;
            int ba1 = (rowa * 128 + 64 + g * 16) ^ swz;
            bf16x8 a0 = *(const bf16x8*)((const char*)Kl[cur] + ba0);
            bf16x8 a1 = *(const bf16x8*)((const char*)Kl[cur] + ba1);
            f32x4 s = {};
            s = MFMA16(a0, bq0, s);
            s = MFMA16(a1, bq1, s);
            int kg = kt * 64 + n * 16 + g * 4;
            float4 mv = *(const float4*)&mrow[kg];
            lsum += (kg + 0 <= qrow) ? __expf(s[0] * 0.03125f + (1.0f - mv.x) * NEGV) : 0.f;
            lsum += (kg + 1 <= qrow) ? __expf(s[1] * 0.03125f + (1.0f - mv.y) * NEGV) : 0.f;
            lsum += (kg + 2 <= qrow) ? __expf(s[2] * 0.03125f + (1.0f - mv.z) * NEGV) : 0.f;
            lsum += (kg + 3 <= qrow) ? __expf(s[3] * 0.03125f + (1.0f - mv.w) * NEGV) : 0.f;
        }
        __syncthreads();
    }
    lsum += __shfl_xor(lsum, 16);
    lsum += __shfl_xor(lsum, 32);
    float rl = 1.0f / lsum;

    // ---- pass 2: probs via Pfh half-tile (128B-line NT flush) + PV ----
    f32x4 cacc[4] = {};
    STAGE_K(0, 0);
    STAGE_V(0, 0);
    __syncthreads();
    for (int kt = 0; kt <= qt; kt++) {
        int cur = kt & 1;
        if (kt < qt) { STAGE_K(cur ^ 1, kt + 1); STAGE_V(cur ^ 1, kt + 1); }
#pragma unroll
        for (int hf = 0; hf < 2; hf++) {
#pragma unroll
            for (int nn = 0; nn < 2; nn++) {
                int n = hf * 2 + nn;
                int rowa = n * 16 + q16;
                int ba0 = (rowa * 128 + g * 16) ^ swz;
                int ba1 = (rowa * 128 + 64 + g * 16) ^ swz;
                bf16x8 a0 = *(const bf16x8*)((const char*)Kl[cur] + ba0);
                bf16x8 a1 = *(const bf16x8*)((const char*)Kl[cur] + ba1);
                f32x4 s = {};
                s = MFMA16(a0, bq0, s);
                s = MFMA16(a1, bq1, s);
                int kg = kt * 64 + n * 16 + g * 4;
                float4 mv = *(const float4*)&mrow[kg];
                float pv[4];
                pv[0] = (kg + 0 <= qrow) ? __expf(s[0] * 0.03125f + (1.0f - mv.x) * NEGV) * rl : 0.f;
                pv[1] = (kg + 1 <= qrow) ? __expf(s[1] * 0.03125f + (1.0f - mv.y) * NEGV) * rl : 0.f;
                pv[2] = (kg + 2 <= qrow) ? __expf(s[2] * 0.03125f + (1.0f - mv.z) * NEGV) * rl : 0.f;
                pv[3] = (kg + 3 <= qrow) ? __expf(s[3] * 0.03125f + (1.0f - mv.w) * NEGV) * rl : 0.f;
                f32x4 st;
                st[0] = pv[0]; st[1] = pv[1]; st[2] = pv[2]; st[3] = pv[3];
                int fb = (q16 * 128 + nn * 64 + g * 16) ^ swz;
                *(f32x4*)((char*)Pfh[w] + fb) = st;
                us4 pk;
#pragma unroll
                for (int r = 0; r < 4; r++) pk[r] = f2bf(pv[r]);
                int wb = (q16 * 128 + n * 32 + g * 8) ^ swz;
                *(us4*)(&Pl[w][wb]) = pk;
            }
            asm volatile("s_waitcnt lgkmcnt(0)" ::: "memory");
            __builtin_amdgcn_sched_barrier(0);
#pragma unroll
            for (int j = 0; j < 2; j++) {
                int row = (l >> 3) + j * 8;
                int rb = (row * 128 + (l & 7) * 16) ^ ((row & 7) << 4);
                f32x4 pvv = *(const f32x4*)((const char*)Pfh[w] + rb);
                __builtin_nontemporal_store(
                    pvv, (f32x4*)&probs[pb + (size_t)(qt * 64 + w * 16 + row) * S +
                                        kt * 64 + hf * 32 + (l & 7) * 4]);
            }
        }
        asm volatile("s_waitcnt lgkmcnt(0)" ::: "memory");
        __builtin_amdgcn_sched_barrier(0);
        bf16x8 pa0, pa1;
        {
            int rb0 = (q16 * 128 + g * 16) ^ swz;
            int rb1 = (q16 * 128 + 64 + g * 16) ^ swz;
            pa0 = *(const bf16x8*)(&Pl[w][rb0]);
            pa1 = *(const bf16x8*)(&Pl[w][rb1]);
        }
#pragma unroll
        for (int n = 0; n < 4; n++) {
            int rowv = n * 16 + q16;
            int bv0 = (rowv * 128 + g * 16) ^ swz;
            int bv1 = (rowv * 128 + 64 + g * 16) ^ swz;
            bf16x8 v0 = *(const bf16x8*)((const char*)Vl[cur] + bv0);
            bf16x8 v1 = *(const bf16x8*)((const char*)Vl[cur] + bv1);
            cacc[n] = MFMA16(pa0, v0, cacc[n]);
            cacc[n] = MFMA16(pa1, v1, cacc[n]);
        }
        asm volatile("s_waitcnt vmcnt(4)" ::: "memory");
        __builtin_amdgcn_s_barrier();
        __builtin_amdgcn_sched_barrier(0);
    }

    // ---- ctx store ----
    u16* cp = ctx + ((size_t)b * S + qt * 64 + w * 16) * D + h * 64;
#pragma unroll
    for (int n = 0; n < 4; n++)
#pragma unroll
        for (int r = 0; r < 4; r++)
            cp[(size_t)(g * 4 + r) * D + n * 16 + q16] = f2bf(cacc[n][r]);

    // ---- zero-fill future-k tiles for this qt (nt, full lines) ----
    for (int kt = qt + 1; kt < 32; kt++) {
        f32x4 z = {0.f, 0.f, 0.f, 0.f};
#pragma unroll
        for (int j = 0; j < 4; j++) {
            int slot = t + j * 256;
            int rr = slot >> 4, c4 = (slot & 15) * 4;
            __builtin_nontemporal_store(
                z, (f32x4*)&probs[pb + (size_t)(qt * 64 + rr) * S + kt * 64 + c4]);
        }
    }
#undef STAGE_K
#undef STAGE_V
}

// ---------------- LayerNorm (block per row) ----------------
__global__ __launch_bounds__(256) void ln_kernel(const float* __restrict__ x,
                                                 const float* __restrict__ gamma,
                                                 const float* __restrict__ beta,
                                                 float* __restrict__ out) {
    int row = blockIdx.x, t = threadIdx.x, w = t >> 6, l = t & 63;
    __shared__ float red[8];
    float4 v = ((const float4*)(x + (size_t)row * 1024))[t];
    float s1 = v.x + v.y + v.z + v.w;
    float s2 = v.x * v.x + v.y * v.y + v.z * v.z + v.w * v.w;
#pragma unroll
    for (int mk = 1; mk < 64; mk <<= 1) {
        s1 += __shfl_xor(s1, mk);
        s2 += __shfl_xor(s2, mk);
    }
    if (l == 0) { red[w] = s1; red[4 + w] = s2; }
    __syncthreads();
    float S1 = red[0] + red[1] + red[2] + red[3];
    float S2 = red[4] + red[5] + red[6] + red[7];
    float mu = S1 * (1.0f / 1024.0f);
    float var = S2 * (1.0f / 1024.0f) - mu * mu;
    float inv = rsqrtf(var + 1e-12f);
    float4 g = ((const float4*)gamma)[t];
    float4 bt = ((const float4*)beta)[t];
    float4 o;
    o.x = g.x * (v.x - mu) * inv + bt.x;
    o.y = g.y * (v.y - mu) * inv + bt.y;
    o.z = g.z * (v.z - mu) * inv + bt.z;
    o.w = g.w * (v.w - mu) * inv + bt.w;
    ((float4*)(out + (size_t)row * 1024))[t] = o;
}

extern "C" void kernel_launch(void* const* d_in, const int* in_sizes, int n_in,
                              void* d_out, int out_size, void* d_ws, size_t ws_size,
                              hipStream_t stream) {
    const float* emb   = (const float*)d_in[0];
    const float* mask  = (const float*)d_in[1];
    const float* Wq    = (const float*)d_in[2];
    const float* bq    = (const float*)d_in[3];
    const float* Wo    = (const float*)d_in[8];
    const float* bo    = (const float*)d_in[9];
    const float* gamma = (const float*)d_in[10];
    const float* beta  = (const float*)d_in[11];
    float* out_ln = (float*)d_out;
    float* probs  = (float*)d_out + (size_t)2 * 2048 * 1024;

    char* ws = (char*)d_ws;
    u16* emb_bf = (u16*)ws; ws += (size_t)8388608;
    u16* Wq_bf  = (u16*)ws; ws += (size_t)2097152;
    u16* Wo_bf  = (u16*)ws; ws += (size_t)2097152;
    u16* Qb     = (u16*)ws; ws += (size_t)8388608;
    u16* Qtb    = (u16*)ws; ws += (size_t)8388608;
    u16* ctxb   = (u16*)ws; ws += (size_t)8388608;
    float* xf   = (float*)ws;

    cvt_bf16<<<4096, 256, 0, stream>>>(emb, emb_bf, 1048576);
    cvt_bf16<<<1024, 256, 0, stream>>>(Wq, Wq_bf, 262144);
    cvt_bf16<<<1024, 256, 0, stream>>>(Wo, Wo_bf, 262144);
    gemm_q_kernel<<<dim3(8, 64), 256, 0, stream>>>(emb_bf, Wq_bf, bq, Qb);
    transpose_q<<<dim3(32, 16, 2), 256, 0, stream>>>(Qb, Qtb);
    attn_kernel<<<1024, 256, 0, stream>>>(Qb, Qtb, mask, probs, ctxb);
    gemm_o_kernel<<<dim3(8, 64), 256, 0, stream>>>(ctxb, Wo_bf, bo, emb, xf);
    ln_kernel<<<4096, 256, 0, stream>>>(xf, gamma, beta, out_ln);
}

// Round 17
// 199.316 us; speedup vs baseline: 1.1166x; 1.0024x over previous
//
#include <hip/hip_runtime.h>
#include <hip/hip_bf16.h>

typedef unsigned short u16;
typedef short bf16x8 __attribute__((ext_vector_type(8)));
typedef float f32x4 __attribute__((ext_vector_type(4)));
typedef u16 us8 __attribute__((ext_vector_type(8)));
typedef u16 us4 __attribute__((ext_vector_type(4)));

#define NEGV -10000.0f

static __device__ __forceinline__ u16 f2bf(float f) {
    __hip_bfloat16 h = __float2bfloat16(f);
    return __builtin_bit_cast(u16, h);
}

#define GLOAD_LDS16(g, l)                                                      \
    __builtin_amdgcn_global_load_lds(                                          \
        (const __attribute__((address_space(1))) void*)(g),                    \
        (__attribute__((address_space(3))) void*)(l), 16, 0, 0)

#define MFMA16(a, b, c) __builtin_amdgcn_mfma_f32_16x16x32_bf16(a, b, c, 0, 0, 0)

// ---------------- fp32 -> bf16 convert ----------------
__global__ __launch_bounds__(256) void cvt_bf16(const float* __restrict__ src,
                                                u16* __restrict__ dst, int n4) {
    int i = blockIdx.x * 256 + threadIdx.x;
    if (i < n4) {
        float4 v = ((const float4*)src)[i];
        ushort4 o;
        o.x = f2bf(v.x); o.y = f2bf(v.y); o.z = f2bf(v.z); o.w = f2bf(v.w);
        ((ushort4*)dst)[i] = o;
    }
}

// ---- GEMM: out_bf16 = A @ B^T + bias. Tile 64x128, BK=64, XOR-swizzled LDS
// (R16: conflict-free fragment reads, 2 barriers per 64-K). ----
__global__ __launch_bounds__(256) void gemm_q_kernel(
    const u16* __restrict__ A, const u16* __restrict__ Bw,
    const float* __restrict__ bias, u16* __restrict__ out) {
    const int K = 1024;
    __shared__ __align__(16) u16 Al[64 * 64];    // 8KB
    __shared__ __align__(16) u16 Bl[128 * 64];   // 16KB
    int t = threadIdx.x, w = t >> 6, l = t & 63;
    int wr = w >> 1, wc = w & 1;
    int row0 = blockIdx.y * 64, col0 = blockIdx.x * 128;
    int srow = t >> 3, schunk = t & 7;
    f32x4 acc[2][4] = {};
    for (int k0 = 0; k0 < K; k0 += 64) {
        __syncthreads();
        {
            int r0 = srow, c0 = (schunk ^ (r0 & 7)) * 8;
            GLOAD_LDS16(A + (size_t)(row0 + r0) * K + k0 + c0, &Al[t * 8]);
            int r1 = srow + 32, c1 = (schunk ^ (r1 & 7)) * 8;
            GLOAD_LDS16(A + (size_t)(row0 + r1) * K + k0 + c1, &Al[2048 + t * 8]);
        }
#pragma unroll
        for (int j = 0; j < 4; j++) {
            int r = srow + j * 32, c = (schunk ^ (r & 7)) * 8;
            GLOAD_LDS16(Bw + (size_t)(col0 + r) * K + k0 + c, &Bl[j * 2048 + t * 8]);
        }
        __syncthreads();
#pragma unroll
        for (int kk = 0; kk < 2; kk++) {
            bf16x8 a[2], b[4];
#pragma unroll
            for (int m = 0; m < 2; m++) {
                int row = wr * 32 + m * 16 + (l & 15);
                int ch = (kk * 4 + (l >> 4)) ^ (row & 7);
                a[m] = *(const bf16x8*)&Al[row * 64 + ch * 8];
            }
#pragma unroll
            for (int n = 0; n < 4; n++) {
                int row = wc * 64 + n * 16 + (l & 15);
                int ch = (kk * 4 + (l >> 4)) ^ (row & 7);
                b[n] = *(const bf16x8*)&Bl[row * 64 + ch * 8];
            }
#pragma unroll
            for (int m = 0; m < 2; m++)
#pragma unroll
                for (int n = 0; n < 4; n++)
                    acc[m][n] = MFMA16(a[m], b[n], acc[m][n]);
        }
    }
    int cr = (l >> 4) * 4, cc = l & 15;
#pragma unroll
    for (int m = 0; m < 2; m++)
#pragma unroll
        for (int n = 0; n < 4; n++) {
            int col = col0 + wc * 64 + n * 16 + cc;
            float bv = bias[col];
#pragma unroll
            for (int r = 0; r < 4; r++) {
                int row = row0 + wr * 32 + m * 16 + cr + r;
                out[(size_t)row * 1024 + col] = f2bf(acc[m][n][r] + bv);
            }
        }
}

// ---- GEMM: x_f32 = A @ B^T + bias + resid. Same BK=64 swizzled tiling. ----
__global__ __launch_bounds__(256) void gemm_o_kernel(
    const u16* __restrict__ A, const u16* __restrict__ Bw,
    const float* __restrict__ bias, const float* __restrict__ resid,
    float* __restrict__ out) {
    const int K = 1024;
    __shared__ __align__(16) u16 Al[64 * 64];
    __shared__ __align__(16) u16 Bl[128 * 64];
    int t = threadIdx.x, w = t >> 6, l = t & 63;
    int wr = w >> 1, wc = w & 1;
    int row0 = blockIdx.y * 64, col0 = blockIdx.x * 128;
    int srow = t >> 3, schunk = t & 7;
    f32x4 acc[2][4] = {};
    for (int k0 = 0; k0 < K; k0 += 64) {
        __syncthreads();
        {
            int r0 = srow, c0 = (schunk ^ (r0 & 7)) * 8;
            GLOAD_LDS16(A + (size_t)(row0 + r0) * K + k0 + c0, &Al[t * 8]);
            int r1 = srow + 32, c1 = (schunk ^ (r1 & 7)) * 8;
            GLOAD_LDS16(A + (size_t)(row0 + r1) * K + k0 + c1, &Al[2048 + t * 8]);
        }
#pragma unroll
        for (int j = 0; j < 4; j++) {
            int r = srow + j * 32, c = (schunk ^ (r & 7)) * 8;
            GLOAD_LDS16(Bw + (size_t)(col0 + r) * K + k0 + c, &Bl[j * 2048 + t * 8]);
        }
        __syncthreads();
#pragma unroll
        for (int kk = 0; kk < 2; kk++) {
            bf16x8 a[2], b[4];
#pragma unroll
            for (int m = 0; m < 2; m++) {
                int row = wr * 32 + m * 16 + (l & 15);
                int ch = (kk * 4 + (l >> 4)) ^ (row & 7);
                a[m] = *(const bf16x8*)&Al[row * 64 + ch * 8];
            }
#pragma unroll
            for (int n = 0; n < 4; n++) {
                int row = wc * 64 + n * 16 + (l & 15);
                int ch = (kk * 4 + (l >> 4)) ^ (row & 7);
                b[n] = *(const bf16x8*)&Bl[row * 64 + ch * 8];
            }
#pragma unroll
            for (int m = 0; m < 2; m++)
#pragma unroll
                for (int n = 0; n < 4; n++)
                    acc[m][n] = MFMA16(a[m], b[n], acc[m][n]);
        }
    }
    int cr = (l >> 4) * 4, cc = l & 15;
#pragma unroll
    for (int m = 0; m < 2; m++)
#pragma unroll
        for (int n = 0; n < 4; n++) {
            int col = col0 + wc * 64 + n * 16 + cc;
            float bv = bias[col];
#pragma unroll
            for (int r = 0; r < 4; r++) {
                int row = row0 + wr * 32 + m * 16 + cr + r;
                out[(size_t)row * 1024 + col] =
                    acc[m][n][r] + bv + resid[(size_t)row * 1024 + col];
            }
        }
}

// ---------------- per-head transpose: Qt[b,h,dh,s] = Q[b,s,h*64+dh] ----------
__global__ __launch_bounds__(256) void transpose_q(const u16* __restrict__ Q,
                                                   u16* __restrict__ Qt) {
    __shared__ u16 T[64][72];
    int t = threadIdx.x;
    int s0 = blockIdx.x * 64, h = blockIdx.y, b = blockIdx.z;
    int c8 = (t & 7) * 8;
#pragma unroll
    for (int half = 0; half < 2; half++) {
        int r = (t >> 3) + half * 32;
        us8 v = *(const us8*)(Q + (size_t)(b * 2048 + s0 + r) * 1024 + h * 64 + c8);
#pragma unroll
        for (int j = 0; j < 8; j++) T[r][c8 + j] = v[j];
    }
    __syncthreads();
    int s8 = (t & 7) * 8;
#pragma unroll
    for (int half = 0; half < 2; half++) {
        int d = (t >> 3) + half * 32;
        us8 o;
#pragma unroll
        for (int j = 0; j < 8; j++) o[j] = T[s8 + j][d];
        *(us8*)(Qt + (size_t)((b * 16 + h) * 64 + d) * 2048 + s0 + s8) = o;
    }
}

// ---------------- fused attention (R17): pass-1 with 128-row K tiles -------
// R17 change (single mechanism): pass-1 stages 128 K-rows per round (4
// gload_lds, same total bytes) -> barrier rounds halve (33->17). LDS: the
// pass-1 dbuf 128-row tile UNIONs with pass-2's K|V buffers (KV[2][8192] u16
// = 32KB; pass 2: K at base 0, V at +8KB) so total stays 48KB / 3 blocks/CU.
// Tail over-compute (k-tiles beyond qt inside the last 128-tile) is zeroed by
// the causal clamp; staged rows and mask loads always in-bounds (<=2048).
// Pass-2 / store path = R14 proven config, byte-identical.
__global__ __launch_bounds__(256, 3) void attn_kernel(
    const u16* __restrict__ Q,    // [B,S,D] bf16
    const u16* __restrict__ Qt,   // [B,H,DH,S] bf16 (V^T per head)
    const float* __restrict__ mask,
    float* __restrict__ probs,    // [B,H,S,S] fp32
    u16* __restrict__ ctx) {      // [B,S,D] bf16
    const int S = 2048, D = 1024;
    __shared__ __align__(16) u16 KV[2][8192];    // 32KB (p1: K128 | p2: K64+V64)
    __shared__ __align__(16) char Pl[4][2048];   // 8KB (bf16 P for PV MFMA)
    __shared__ __align__(16) float Pfh[4][512];  // 8KB (f32 P half, 128B/row)
    int id = blockIdx.x;
    int wgid = (id & 7) * 128 + (id >> 3);      // XCD swizzle (1024 % 8 == 0)
    int qt = 31 - (wgid & 31);                  // qt descending in launch order
    int h = (wgid >> 5) & 15, b = wgid >> 9;
    int t = threadIdx.x, w = t >> 6, l = t & 63;
    int g = l >> 4, q16 = l & 15;
    size_t pb = ((size_t)(b * 16 + h)) * S * S;
    const u16* Qh = Q + (size_t)b * S * D + h * 64;        // row stride D
    const u16* Vh = Qt + ((size_t)(b * 16 + h) * 64) * S;  // row stride S
    const float* mrow = mask + b * S;

    int krow0 = t >> 3, kc0 = (((t & 7) ^ (krow0 & 7)) * 8);
    int krow1 = (t >> 3) + 32, kc1 = (((t & 7) ^ (krow1 & 7)) * 8);

// pass-2 staging: K tile at KV[buf][0..4096), V tile at KV[buf][4096..8192)
#define STAGE_K(buf, kt)                                                        \
    do {                                                                        \
        GLOAD_LDS16(Qh + (size_t)((kt) * 64 + krow0) * D + kc0, &KV[buf][t * 8]);\
        GLOAD_LDS16(Qh + (size_t)((kt) * 64 + krow1) * D + kc1,                  \
                    &KV[buf][2048 + t * 8]);                                     \
    } while (0)
#define STAGE_V(buf, kt)                                                        \
    do {                                                                        \
        GLOAD_LDS16(Vh + (size_t)krow0 * S + (kt) * 64 + kc0,                    \
                    &KV[buf][4096 + t * 8]);                                     \
        GLOAD_LDS16(Vh + (size_t)krow1 * S + (kt) * 64 + kc1,                    \
                    &KV[buf][6144 + t * 8]);                                     \
    } while (0)
// pass-1 staging: 128 K rows into KV[buf][0..8192)
#define STAGE_K2(buf, kt2)                                                      \
    do {                                                                        \
        _Pragma("unroll")                                                       \
        for (int j = 0; j < 4; j++) {                                           \
            int r = j * 32 + (t >> 3);                                          \
            int c = ((t & 7) ^ (r & 7)) * 8;                                    \
            GLOAD_LDS16(Qh + (size_t)((kt2) * 128 + r) * D + c,                  \
                        &KV[buf][j * 2048 + t * 8]);                             \
        }                                                                       \
    } while (0)

    int swz = (q16 & 7) << 4;
    int qrow = qt * 64 + w * 16 + q16;
    const u16* qp = Qh + (size_t)qrow * D;
    bf16x8 bq0 = *(const bf16x8*)(qp + g * 8);
    bf16x8 bq1 = *(const bf16x8*)(qp + 32 + g * 8);

    // ---- pass 1: row sums of exp(s), 128-row K tiles ----
    float lsum = 0.f;
    int nk2 = (qt + 2) >> 1;   // 128-row tiles covering k-tiles 0..qt
    STAGE_K2(0, 0);
    __syncthreads();
    for (int kt2 = 0; kt2 < nk2; kt2++) {
        int cur = kt2 & 1;
        if (kt2 + 1 < nk2) STAGE_K2(cur ^ 1, kt2 + 1);
#pragma unroll
        for (int n = 0; n < 8; n++) {
            int rowa = n * 16 + q16;
            int ba0 = (rowa * 128 + g * 16) ^ swz;
            int ba1 = (rowa * 128 + 64 + g * 16) ^ swz;
            bf16x8 a0 = *(const bf16x8*)((const char*)KV[cur] + ba0);
            bf16x8 a1 = *(const bf16x8*)((const char*)KV[cur] + ba1);
            f32x4 s = {};
            s = MFMA16(a0, bq0, s);
            s = MFMA16(a1, bq1, s);
            int kg = kt2 * 128 + n * 16 + g * 4;
            float4 mv = *(const float4*)&mrow[kg];
            lsum += (kg + 0 <= qrow) ? __expf(s[0] * 0.03125f + (1.0f - mv.x) * NEGV) : 0.f;
            lsum += (kg + 1 <= qrow) ? __expf(s[1] * 0.03125f + (1.0f - mv.y) * NEGV) : 0.f;
            lsum += (kg + 2 <= qrow) ? __expf(s[2] * 0.03125f + (1.0f - mv.z) * NEGV) : 0.f;
            lsum += (kg + 3 <= qrow) ? __expf(s[3] * 0.03125f + (1.0f - mv.w) * NEGV) : 0.f;
        }
        __syncthreads();
    }
    lsum += __shfl_xor(lsum, 16);
    lsum += __shfl_xor(lsum, 32);
    float rl = 1.0f / lsum;

    // ---- pass 2: probs via Pfh half-tile (128B-line NT flush) + PV ----
    f32x4 cacc[4] = {};
    STAGE_K(0, 0);
    STAGE_V(0, 0);
    __syncthreads();
    for (int kt = 0; kt <= qt; kt++) {
        int cur = kt & 1;
        if (kt < qt) { STAGE_K(cur ^ 1, kt + 1); STAGE_V(cur ^ 1, kt + 1); }
#pragma unroll
        for (int hf = 0; hf < 2; hf++) {
#pragma unroll
            for (int nn = 0; nn < 2; nn++) {
                int n = hf * 2 + nn;
                int rowa = n * 16 + q16;
                int ba0 = (rowa * 128 + g * 16) ^ swz;
                int ba1 = (rowa * 128 + 64 + g * 16) ^ swz;
                bf16x8 a0 = *(const bf16x8*)((const char*)KV[cur] + ba0);
                bf16x8 a1 = *(const bf16x8*)((const char*)KV[cur] + ba1);
                f32x4 s = {};
                s = MFMA16(a0, bq0, s);
                s = MFMA16(a1, bq1, s);
                int kg = kt * 64 + n * 16 + g * 4;
                float4 mv = *(const float4*)&mrow[kg];
                float pv[4];
                pv[0] = (kg + 0 <= qrow) ? __expf(s[0] * 0.03125f + (1.0f - mv.x) * NEGV) * rl : 0.f;
                pv[1] = (kg + 1 <= qrow) ? __expf(s[1] * 0.03125f + (1.0f - mv.y) * NEGV) * rl : 0.f;
                pv[2] = (kg + 2 <= qrow) ? __expf(s[2] * 0.03125f + (1.0f - mv.z) * NEGV) * rl : 0.f;
                pv[3] = (kg + 3 <= qrow) ? __expf(s[3] * 0.03125f + (1.0f - mv.w) * NEGV) * rl : 0.f;
                f32x4 st;
                st[0] = pv[0]; st[1] = pv[1]; st[2] = pv[2]; st[3] = pv[3];
                int fb = (q16 * 128 + nn * 64 + g * 16) ^ swz;
                *(f32x4*)((char*)Pfh[w] + fb) = st;
                us4 pk;
#pragma unroll
                for (int r = 0; r < 4; r++) pk[r] = f2bf(pv[r]);
                int wb = (q16 * 128 + n * 32 + g * 8) ^ swz;
                *(us4*)(&Pl[w][wb]) = pk;
            }
            asm volatile("s_waitcnt lgkmcnt(0)" ::: "memory");
            __builtin_amdgcn_sched_barrier(0);
#pragma unroll
            for (int j = 0; j < 2; j++) {
                int row = (l >> 3) + j * 8;
                int rb = (row * 128 + (l & 7) * 16) ^ ((row & 7) << 4);
                f32x4 pvv = *(const f32x4*)((const char*)Pfh[w] + rb);
                __builtin_nontemporal_store(
                    pvv, (f32x4*)&probs[pb + (size_t)(qt * 64 + w * 16 + row) * S +
                                        kt * 64 + hf * 32 + (l & 7) * 4]);
            }
        }
        asm volatile("s_waitcnt lgkmcnt(0)" ::: "memory");
        __builtin_amdgcn_sched_barrier(0);
        bf16x8 pa0, pa1;
        {
            int rb0 = (q16 * 128 + g * 16) ^ swz;
            int rb1 = (q16 * 128 + 64 + g * 16) ^ swz;
            pa0 = *(const bf16x8*)(&Pl[w][rb0]);
            pa1 = *(const bf16x8*)(&Pl[w][rb1]);
        }
#pragma unroll
        for (int n = 0; n < 4; n++) {
            int rowv = n * 16 + q16;
            int bv0 = (8192 + ((rowv * 128 + g * 16) ^ swz));
            int bv1 = (8192 + ((rowv * 128 + 64 + g * 16) ^ swz));
            bf16x8 v0 = *(const bf16x8*)((const char*)KV[cur] + bv0);
            bf16x8 v1 = *(const bf16x8*)((const char*)KV[cur] + bv1);
            cacc[n] = MFMA16(pa0, v0, cacc[n]);
            cacc[n] = MFMA16(pa1, v1, cacc[n]);
        }
        asm volatile("s_waitcnt vmcnt(4)" ::: "memory");
        __builtin_amdgcn_s_barrier();
        __builtin_amdgcn_sched_barrier(0);
    }

    // ---- ctx store ----
    u16* cp = ctx + ((size_t)b * S + qt * 64 + w * 16) * D + h * 64;
#pragma unroll
    for (int n = 0; n < 4; n++)
#pragma unroll
        for (int r = 0; r < 4; r++)
            cp[(size_t)(g * 4 + r) * D + n * 16 + q16] = f2bf(cacc[n][r]);

    // ---- zero-fill future-k tiles for this qt (nt, full lines) ----
    for (int kt = qt + 1; kt < 32; kt++) {
        f32x4 z = {0.f, 0.f, 0.f, 0.f};
#pragma unroll
        for (int j = 0; j < 4; j++) {
            int slot = t + j * 256;
            int rr = slot >> 4, c4 = (slot & 15) * 4;
            __builtin_nontemporal_store(
                z, (f32x4*)&probs[pb + (size_t)(qt * 64 + rr) * S + kt * 64 + c4]);
        }
    }
#undef STAGE_K
#undef STAGE_V
#undef STAGE_K2
}

// ---------------- LayerNorm (block per row) ----------------
__global__ __launch_bounds__(256) void ln_kernel(const float* __restrict__ x,
                                                 const float* __restrict__ gamma,
                                                 const float* __restrict__ beta,
                                                 float* __restrict__ out) {
    int row = blockIdx.x, t = threadIdx.x, w = t >> 6, l = t & 63;
    __shared__ float red[8];
    float4 v = ((const float4*)(x + (size_t)row * 1024))[t];
    float s1 = v.x + v.y + v.z + v.w;
    float s2 = v.x * v.x + v.y * v.y + v.z * v.z + v.w * v.w;
#pragma unroll
    for (int mk = 1; mk < 64; mk <<= 1) {
        s1 += __shfl_xor(s1, mk);
        s2 += __shfl_xor(s2, mk);
    }
    if (l == 0) { red[w] = s1; red[4 + w] = s2; }
    __syncthreads();
    float S1 = red[0] + red[1] + red[2] + red[3];
    float S2 = red[4] + red[5] + red[6] + red[7];
    float mu = S1 * (1.0f / 1024.0f);
    float var = S2 * (1.0f / 1024.0f) - mu * mu;
    float inv = rsqrtf(var + 1e-12f);
    float4 g = ((const float4*)gamma)[t];
    float4 bt = ((const float4*)beta)[t];
    float4 o;
    o.x = g.x * (v.x - mu) * inv + bt.x;
    o.y = g.y * (v.y - mu) * inv + bt.y;
    o.z = g.z * (v.z - mu) * inv + bt.z;
    o.w = g.w * (v.w - mu) * inv + bt.w;
    ((float4*)(out + (size_t)row * 1024))[t] = o;
}

extern "C" void kernel_launch(void* const* d_in, const int* in_sizes, int n_in,
                              void* d_out, int out_size, void* d_ws, size_t ws_size,
                              hipStream_t stream) {
    const float* emb   = (const float*)d_in[0];
    const float* mask  = (const float*)d_in[1];
    const float* Wq    = (const float*)d_in[2];
    const float* bq    = (const float*)d_in[3];
    const float* Wo    = (const float*)d_in[8];
    const float* bo    = (const float*)d_in[9];
    const float* gamma = (const float*)d_in[10];
    const float* beta  = (const float*)d_in[11];
    float* out_ln = (float*)d_out;
    float* probs  = (float*)d_out + (size_t)2 * 2048 * 1024;

    char* ws = (char*)d_ws;
    u16* emb_bf = (u16*)ws; ws += (size_t)8388608;
    u16* Wq_bf  = (u16*)ws; ws += (size_t)2097152;
    u16* Wo_bf  = (u16*)ws; ws += (size_t)2097152;
    u16* Qb     = (u16*)ws; ws += (size_t)8388608;
    u16* Qtb    = (u16*)ws; ws += (size_t)8388608;
    u16* ctxb   = (u16*)ws; ws += (size_t)8388608;
    float* xf   = (float*)ws;

    cvt_bf16<<<4096, 256, 0, stream>>>(emb, emb_bf, 1048576);
    cvt_bf16<<<1024, 256, 0, stream>>>(Wq, Wq_bf, 262144);
    cvt_bf16<<<1024, 256, 0, stream>>>(Wo, Wo_bf, 262144);
    gemm_q_kernel<<<dim3(8, 64), 256, 0, stream>>>(emb_bf, Wq_bf, bq, Qb);
    transpose_q<<<dim3(32, 16, 2), 256, 0, stream>>>(Qb, Qtb);
    attn_kernel<<<1024, 256, 0, stream>>>(Qb, Qtb, mask, probs, ctxb);
    gemm_o_kernel<<<dim3(8, 64), 256, 0, stream>>>(ctxb, Wo_bf, bo, emb, xf);
    ln_kernel<<<4096, 256, 0, stream>>>(xf, gamma, beta, out_ln);
}

// Round 18
// 195.224 us; speedup vs baseline: 1.1400x; 1.0210x over previous
//
#include <hip/hip_runtime.h>
#include <hip/hip_bf16.h>

typedef unsigned short u16;
typedef short bf16x8 __attribute__((ext_vector_type(8)));
typedef float f32x4 __attribute__((ext_vector_type(4)));
typedef u16 us8 __attribute__((ext_vector_type(8)));
typedef u16 us4 __attribute__((ext_vector_type(4)));

#define NEGV -10000.0f

static __device__ __forceinline__ u16 f2bf(float f) {
    __hip_bfloat16 h = __float2bfloat16(f);
    return __builtin_bit_cast(u16, h);
}

#define GLOAD_LDS16(g, l)                                                      \
    __builtin_amdgcn_global_load_lds(                                          \
        (const __attribute__((address_space(1))) void*)(g),                    \
        (__attribute__((address_space(3))) void*)(l), 16, 0, 0)

#define MFMA16(a, b, c) __builtin_amdgcn_mfma_f32_16x16x32_bf16(a, b, c, 0, 0, 0)

// ---------------- fp32 -> bf16 convert, 3 tensors in one launch ------------
__global__ __launch_bounds__(256) void cvt3(const float* __restrict__ a,
                                            const float* __restrict__ bsrc,
                                            const float* __restrict__ c,
                                            u16* __restrict__ da,
                                            u16* __restrict__ db,
                                            u16* __restrict__ dc) {
    int i = blockIdx.x * 256 + threadIdx.x;
    const float* src;
    u16* dst;
    int off;
    if (i < 1048576) { src = a; dst = da; off = i; }
    else if (i < 1310720) { src = bsrc; dst = db; off = i - 1048576; }
    else { src = c; dst = dc; off = i - 1310720; }
    float4 v = ((const float4*)src)[off];
    ushort4 o;
    o.x = f2bf(v.x); o.y = f2bf(v.y); o.z = f2bf(v.z); o.w = f2bf(v.w);
    ((ushort4*)dst)[off] = o;
}

// ---- GEMM Q: out_bf16 = A @ B^T + bias, PLUS fused per-head transpose
// Qt[b,h,dh,s]. Tile 64x128, BK=64, XOR-swizzled LDS (R16 conflict-free).
// Epilogue: biased bf16 values go to Tq[64][136] (padded), barrier, then
// 8-lanes-per-row us8 writes to Qt (same coalescing as old transpose kernel).
__global__ __launch_bounds__(256) void gemm_q_kernel(
    const u16* __restrict__ A, const u16* __restrict__ Bw,
    const float* __restrict__ bias, u16* __restrict__ out,
    u16* __restrict__ Qt) {
    const int K = 1024;
    __shared__ __align__(16) u16 Al[64 * 64];    // 8KB
    __shared__ __align__(16) u16 Bl[128 * 64];   // 16KB
    __shared__ __align__(16) u16 Tq[64 * 136];   // 17KB (pad 8 breaks conflicts)
    int t = threadIdx.x, w = t >> 6, l = t & 63;
    int wr = w >> 1, wc = w & 1;
    int row0 = blockIdx.y * 64, col0 = blockIdx.x * 128;
    int srow = t >> 3, schunk = t & 7;
    f32x4 acc[2][4] = {};
    for (int k0 = 0; k0 < K; k0 += 64) {
        __syncthreads();
        {
            int r0 = srow, c0 = (schunk ^ (r0 & 7)) * 8;
            GLOAD_LDS16(A + (size_t)(row0 + r0) * K + k0 + c0, &Al[t * 8]);
            int r1 = srow + 32, c1 = (schunk ^ (r1 & 7)) * 8;
            GLOAD_LDS16(A + (size_t)(row0 + r1) * K + k0 + c1, &Al[2048 + t * 8]);
        }
#pragma unroll
        for (int j = 0; j < 4; j++) {
            int r = srow + j * 32, c = (schunk ^ (r & 7)) * 8;
            GLOAD_LDS16(Bw + (size_t)(col0 + r) * K + k0 + c, &Bl[j * 2048 + t * 8]);
        }
        __syncthreads();
#pragma unroll
        for (int kk = 0; kk < 2; kk++) {
            bf16x8 a[2], b[4];
#pragma unroll
            for (int m = 0; m < 2; m++) {
                int row = wr * 32 + m * 16 + (l & 15);
                int ch = (kk * 4 + (l >> 4)) ^ (row & 7);
                a[m] = *(const bf16x8*)&Al[row * 64 + ch * 8];
            }
#pragma unroll
            for (int n = 0; n < 4; n++) {
                int row = wc * 64 + n * 16 + (l & 15);
                int ch = (kk * 4 + (l >> 4)) ^ (row & 7);
                b[n] = *(const bf16x8*)&Bl[row * 64 + ch * 8];
            }
#pragma unroll
            for (int m = 0; m < 2; m++)
#pragma unroll
                for (int n = 0; n < 4; n++)
                    acc[m][n] = MFMA16(a[m], b[n], acc[m][n]);
        }
    }
    int cr = (l >> 4) * 4, cc = l & 15;
#pragma unroll
    for (int m = 0; m < 2; m++)
#pragma unroll
        for (int n = 0; n < 4; n++) {
            int lc = wc * 64 + n * 16 + cc;
            int col = col0 + lc;
            float bv = bias[col];
#pragma unroll
            for (int r = 0; r < 4; r++) {
                int lr = wr * 32 + m * 16 + cr + r;
                u16 qv = f2bf(acc[m][n][r] + bv);
                out[(size_t)(row0 + lr) * 1024 + col] = qv;
                Tq[lr * 136 + lc] = qv;
            }
        }
    __syncthreads();
    // transposed write: Qt[b, h0+(d>>6), d&63, s0+s8..] ; 8 lanes cover one
    // 128B s-run per dh-row (coalescing identical to old transpose kernel).
    {
        int b_ = row0 >> 11, s0 = row0 & 2047, h0 = col0 >> 6;
        int s8 = (t & 7) * 8;
#pragma unroll
        for (int half = 0; half < 4; half++) {
            int d = (t >> 3) + half * 32;
            us8 o;
#pragma unroll
            for (int e = 0; e < 8; e++) o[e] = Tq[(s8 + e) * 136 + d];
            *(us8*)(Qt + ((size_t)((b_ * 16 + h0 + (d >> 6)) * 64 + (d & 63))) * 2048 +
                    s0 + s8) = o;
        }
    }
}

// ---- GEMM: x_f32 = A @ B^T + bias + resid. Same BK=64 swizzled tiling. ----
__global__ __launch_bounds__(256) void gemm_o_kernel(
    const u16* __restrict__ A, const u16* __restrict__ Bw,
    const float* __restrict__ bias, const float* __restrict__ resid,
    float* __restrict__ out) {
    const int K = 1024;
    __shared__ __align__(16) u16 Al[64 * 64];
    __shared__ __align__(16) u16 Bl[128 * 64];
    int t = threadIdx.x, w = t >> 6, l = t & 63;
    int wr = w >> 1, wc = w & 1;
    int row0 = blockIdx.y * 64, col0 = blockIdx.x * 128;
    int srow = t >> 3, schunk = t & 7;
    f32x4 acc[2][4] = {};
    for (int k0 = 0; k0 < K; k0 += 64) {
        __syncthreads();
        {
            int r0 = srow, c0 = (schunk ^ (r0 & 7)) * 8;
            GLOAD_LDS16(A + (size_t)(row0 + r0) * K + k0 + c0, &Al[t * 8]);
            int r1 = srow + 32, c1 = (schunk ^ (r1 & 7)) * 8;
            GLOAD_LDS16(A + (size_t)(row0 + r1) * K + k0 + c1, &Al[2048 + t * 8]);
        }
#pragma unroll
        for (int j = 0; j < 4; j++) {
            int r = srow + j * 32, c = (schunk ^ (r & 7)) * 8;
            GLOAD_LDS16(Bw + (size_t)(col0 + r) * K + k0 + c, &Bl[j * 2048 + t * 8]);
        }
        __syncthreads();
#pragma unroll
        for (int kk = 0; kk < 2; kk++) {
            bf16x8 a[2], b[4];
#pragma unroll
            for (int m = 0; m < 2; m++) {
                int row = wr * 32 + m * 16 + (l & 15);
                int ch = (kk * 4 + (l >> 4)) ^ (row & 7);
                a[m] = *(const bf16x8*)&Al[row * 64 + ch * 8];
            }
#pragma unroll
            for (int n = 0; n < 4; n++) {
                int row = wc * 64 + n * 16 + (l & 15);
                int ch = (kk * 4 + (l >> 4)) ^ (row & 7);
                b[n] = *(const bf16x8*)&Bl[row * 64 + ch * 8];
            }
#pragma unroll
            for (int m = 0; m < 2; m++)
#pragma unroll
                for (int n = 0; n < 4; n++)
                    acc[m][n] = MFMA16(a[m], b[n], acc[m][n]);
        }
    }
    int cr = (l >> 4) * 4, cc = l & 15;
#pragma unroll
    for (int m = 0; m < 2; m++)
#pragma unroll
        for (int n = 0; n < 4; n++) {
            int col = col0 + wc * 64 + n * 16 + cc;
            float bv = bias[col];
#pragma unroll
            for (int r = 0; r < 4; r++) {
                int row = row0 + wr * 32 + m * 16 + cr + r;
                out[(size_t)row * 1024 + col] =
                    acc[m][n][r] + bv + resid[(size_t)row * 1024 + col];
            }
        }
}

// ---------------- fused attention (R17 config, best measured) --------------
__global__ __launch_bounds__(256, 3) void attn_kernel(
    const u16* __restrict__ Q,    // [B,S,D] bf16
    const u16* __restrict__ Qt,   // [B,H,DH,S] bf16 (V^T per head)
    const float* __restrict__ mask,
    float* __restrict__ probs,    // [B,H,S,S] fp32
    u16* __restrict__ ctx) {      // [B,S,D] bf16
    const int S = 2048, D = 1024;
    __shared__ __align__(16) u16 KV[2][8192];    // 32KB (p1: K128 | p2: K64+V64)
    __shared__ __align__(16) char Pl[4][2048];   // 8KB (bf16 P for PV MFMA)
    __shared__ __align__(16) float Pfh[4][512];  // 8KB (f32 P half, 128B/row)
    int id = blockIdx.x;
    int wgid = (id & 7) * 128 + (id >> 3);      // XCD swizzle (1024 % 8 == 0)
    int qt = 31 - (wgid & 31);                  // qt descending in launch order
    int h = (wgid >> 5) & 15, b = wgid >> 9;
    int t = threadIdx.x, w = t >> 6, l = t & 63;
    int g = l >> 4, q16 = l & 15;
    size_t pb = ((size_t)(b * 16 + h)) * S * S;
    const u16* Qh = Q + (size_t)b * S * D + h * 64;        // row stride D
    const u16* Vh = Qt + ((size_t)(b * 16 + h) * 64) * S;  // row stride S
    const float* mrow = mask + b * S;

    int krow0 = t >> 3, kc0 = (((t & 7) ^ (krow0 & 7)) * 8);
    int krow1 = (t >> 3) + 32, kc1 = (((t & 7) ^ (krow1 & 7)) * 8);

#define STAGE_K(buf, kt)                                                        \
    do {                                                                        \
        GLOAD_LDS16(Qh + (size_t)((kt) * 64 + krow0) * D + kc0, &KV[buf][t * 8]);\
        GLOAD_LDS16(Qh + (size_t)((kt) * 64 + krow1) * D + kc1,                  \
                    &KV[buf][2048 + t * 8]);                                     \
    } while (0)
#define STAGE_V(buf, kt)                                                        \
    do {                                                                        \
        GLOAD_LDS16(Vh + (size_t)krow0 * S + (kt) * 64 + kc0,                    \
                    &KV[buf][4096 + t * 8]);                                     \
        GLOAD_LDS16(Vh + (size_t)krow1 * S + (kt) * 64 + kc1,                    \
                    &KV[buf][6144 + t * 8]);                                     \
    } while (0)
#define STAGE_K2(buf, kt2)                                                      \
    do {                                                                        \
        _Pragma("unroll")                                                       \
        for (int j = 0; j < 4; j++) {                                           \
            int r = j * 32 + (t >> 3);                                          \
            int c = ((t & 7) ^ (r & 7)) * 8;                                    \
            GLOAD_LDS16(Qh + (size_t)((kt2) * 128 + r) * D + c,                  \
                        &KV[buf][j * 2048 + t * 8]);                             \
        }                                                                       \
    } while (0)

    int swz = (q16 & 7) << 4;
    int qrow = qt * 64 + w * 16 + q16;
    const u16* qp = Qh + (size_t)qrow * D;
    bf16x8 bq0 = *(const bf16x8*)(qp + g * 8);
    bf16x8 bq1 = *(const bf16x8*)(qp + 32 + g * 8);

    // ---- pass 1: row sums of exp(s), 128-row K tiles ----
    float lsum = 0.f;
    int nk2 = (qt + 2) >> 1;
    STAGE_K2(0, 0);
    __syncthreads();
    for (int kt2 = 0; kt2 < nk2; kt2++) {
        int cur = kt2 & 1;
        if (kt2 + 1 < nk2) STAGE_K2(cur ^ 1, kt2 + 1);
#pragma unroll
        for (int n = 0; n < 8; n++) {
            int rowa = n * 16 + q16;
            int ba0 = (rowa * 128 + g * 16) ^ swz;
            int ba1 = (rowa * 128 + 64 + g * 16) ^ swz;
            bf16x8 a0 = *(const bf16x8*)((const char*)KV[cur] + ba0);
            bf16x8 a1 = *(const bf16x8*)((const char*)KV[cur] + ba1);
            f32x4 s = {};
            s = MFMA16(a0, bq0, s);
            s = MFMA16(a1, bq1, s);
            int kg = kt2 * 128 + n * 16 + g * 4;
            float4 mv = *(const float4*)&mrow[kg];
            lsum += (kg + 0 <= qrow) ? __expf(s[0] * 0.03125f + (1.0f - mv.x) * NEGV) : 0.f;
            lsum += (kg + 1 <= qrow) ? __expf(s[1] * 0.03125f + (1.0f - mv.y) * NEGV) : 0.f;
            lsum += (kg + 2 <= qrow) ? __expf(s[2] * 0.03125f + (1.0f - mv.z) * NEGV) : 0.f;
            lsum += (kg + 3 <= qrow) ? __expf(s[3] * 0.03125f + (1.0f - mv.w) * NEGV) : 0.f;
        }
        __syncthreads();
    }
    lsum += __shfl_xor(lsum, 16);
    lsum += __shfl_xor(lsum, 32);
    float rl = 1.0f / lsum;

    // ---- pass 2: probs via Pfh half-tile (128B-line NT flush) + PV ----
    f32x4 cacc[4] = {};
    STAGE_K(0, 0);
    STAGE_V(0, 0);
    __syncthreads();
    for (int kt = 0; kt <= qt; kt++) {
        int cur = kt & 1;
        if (kt < qt) { STAGE_K(cur ^ 1, kt + 1); STAGE_V(cur ^ 1, kt + 1); }
#pragma unroll
        for (int hf = 0; hf < 2; hf++) {
#pragma unroll
            for (int nn = 0; nn < 2; nn++) {
                int n = hf * 2 + nn;
                int rowa = n * 16 + q16;
                int ba0 = (rowa * 128 + g * 16) ^ swz;
                int ba1 = (rowa * 128 + 64 + g * 16) ^ swz;
                bf16x8 a0 = *(const bf16x8*)((const char*)KV[cur] + ba0);
                bf16x8 a1 = *(const bf16x8*)((const char*)KV[cur] + ba1);
                f32x4 s = {};
                s = MFMA16(a0, bq0, s);
                s = MFMA16(a1, bq1, s);
                int kg = kt * 64 + n * 16 + g * 4;
                float4 mv = *(const float4*)&mrow[kg];
                float pv[4];
                pv[0] = (kg + 0 <= qrow) ? __expf(s[0] * 0.03125f + (1.0f - mv.x) * NEGV) * rl : 0.f;
                pv[1] = (kg + 1 <= qrow) ? __expf(s[1] * 0.03125f + (1.0f - mv.y) * NEGV) * rl : 0.f;
                pv[2] = (kg + 2 <= qrow) ? __expf(s[2] * 0.03125f + (1.0f - mv.z) * NEGV) * rl : 0.f;
                pv[3] = (kg + 3 <= qrow) ? __expf(s[3] * 0.03125f + (1.0f - mv.w) * NEGV) * rl : 0.f;
                f32x4 st;
                st[0] = pv[0]; st[1] = pv[1]; st[2] = pv[2]; st[3] = pv[3];
                int fb = (q16 * 128 + nn * 64 + g * 16) ^ swz;
                *(f32x4*)((char*)Pfh[w] + fb) = st;
                us4 pk;
#pragma unroll
                for (int r = 0; r < 4; r++) pk[r] = f2bf(pv[r]);
                int wb = (q16 * 128 + n * 32 + g * 8) ^ swz;
                *(us4*)(&Pl[w][wb]) = pk;
            }
            asm volatile("s_waitcnt lgkmcnt(0)" ::: "memory");
            __builtin_amdgcn_sched_barrier(0);
#pragma unroll
            for (int j = 0; j < 2; j++) {
                int row = (l >> 3) + j * 8;
                int rb = (row * 128 + (l & 7) * 16) ^ ((row & 7) << 4);
                f32x4 pvv = *(const f32x4*)((const char*)Pfh[w] + rb);
                __builtin_nontemporal_store(
                    pvv, (f32x4*)&probs[pb + (size_t)(qt * 64 + w * 16 + row) * S +
                                        kt * 64 + hf * 32 + (l & 7) * 4]);
            }
        }
        asm volatile("s_waitcnt lgkmcnt(0)" ::: "memory");
        __builtin_amdgcn_sched_barrier(0);
        bf16x8 pa0, pa1;
        {
            int rb0 = (q16 * 128 + g * 16) ^ swz;
            int rb1 = (q16 * 128 + 64 + g * 16) ^ swz;
            pa0 = *(const bf16x8*)(&Pl[w][rb0]);
            pa1 = *(const bf16x8*)(&Pl[w][rb1]);
        }
#pragma unroll
        for (int n = 0; n < 4; n++) {
            int rowv = n * 16 + q16;
            int bv0 = (8192 + ((rowv * 128 + g * 16) ^ swz));
            int bv1 = (8192 + ((rowv * 128 + 64 + g * 16) ^ swz));
            bf16x8 v0 = *(const bf16x8*)((const char*)KV[cur] + bv0);
            bf16x8 v1 = *(const bf16x8*)((const char*)KV[cur] + bv1);
            cacc[n] = MFMA16(pa0, v0, cacc[n]);
            cacc[n] = MFMA16(pa1, v1, cacc[n]);
        }
        asm volatile("s_waitcnt vmcnt(4)" ::: "memory");
        __builtin_amdgcn_s_barrier();
        __builtin_amdgcn_sched_barrier(0);
    }

    // ---- ctx store ----
    u16* cp = ctx + ((size_t)b * S + qt * 64 + w * 16) * D + h * 64;
#pragma unroll
    for (int n = 0; n < 4; n++)
#pragma unroll
        for (int r = 0; r < 4; r++)
            cp[(size_t)(g * 4 + r) * D + n * 16 + q16] = f2bf(cacc[n][r]);

    // ---- zero-fill future-k tiles for this qt (nt, full lines) ----
    for (int kt = qt + 1; kt < 32; kt++) {
        f32x4 z = {0.f, 0.f, 0.f, 0.f};
#pragma unroll
        for (int j = 0; j < 4; j++) {
            int slot = t + j * 256;
            int rr = slot >> 4, c4 = (slot & 15) * 4;
            __builtin_nontemporal_store(
                z, (f32x4*)&probs[pb + (size_t)(qt * 64 + rr) * S + kt * 64 + c4]);
        }
    }
#undef STAGE_K
#undef STAGE_V
#undef STAGE_K2
}

// ---------------- LayerNorm (block per row) ----------------
__global__ __launch_bounds__(256) void ln_kernel(const float* __restrict__ x,
                                                 const float* __restrict__ gamma,
                                                 const float* __restrict__ beta,
                                                 float* __restrict__ out) {
    int row = blockIdx.x, t = threadIdx.x, w = t >> 6, l = t & 63;
    __shared__ float red[8];
    float4 v = ((const float4*)(x + (size_t)row * 1024))[t];
    float s1 = v.x + v.y + v.z + v.w;
    float s2 = v.x * v.x + v.y * v.y + v.z * v.z + v.w * v.w;
#pragma unroll
    for (int mk = 1; mk < 64; mk <<= 1) {
        s1 += __shfl_xor(s1, mk);
        s2 += __shfl_xor(s2, mk);
    }
    if (l == 0) { red[w] = s1; red[4 + w] = s2; }
    __syncthreads();
    float S1 = red[0] + red[1] + red[2] + red[3];
    float S2 = red[4] + red[5] + red[6] + red[7];
    float mu = S1 * (1.0f / 1024.0f);
    float var = S2 * (1.0f / 1024.0f) - mu * mu;
    float inv = rsqrtf(var + 1e-12f);
    float4 g = ((const float4*)gamma)[t];
    float4 bt = ((const float4*)beta)[t];
    float4 o;
    o.x = g.x * (v.x - mu) * inv + bt.x;
    o.y = g.y * (v.y - mu) * inv + bt.y;
    o.z = g.z * (v.z - mu) * inv + bt.z;
    o.w = g.w * (v.w - mu) * inv + bt.w;
    ((float4*)(out + (size_t)row * 1024))[t] = o;
}

extern "C" void kernel_launch(void* const* d_in, const int* in_sizes, int n_in,
                              void* d_out, int out_size, void* d_ws, size_t ws_size,
                              hipStream_t stream) {
    const float* emb   = (const float*)d_in[0];
    const float* mask  = (const float*)d_in[1];
    const float* Wq    = (const float*)d_in[2];
    const float* bq    = (const float*)d_in[3];
    const float* Wo    = (const float*)d_in[8];
    const float* bo    = (const float*)d_in[9];
    const float* gamma = (const float*)d_in[10];
    const float* beta  = (const float*)d_in[11];
    float* out_ln = (float*)d_out;
    float* probs  = (float*)d_out + (size_t)2 * 2048 * 1024;

    char* ws = (char*)d_ws;
    u16* emb_bf = (u16*)ws; ws += (size_t)8388608;
    u16* Wq_bf  = (u16*)ws; ws += (size_t)2097152;
    u16* Wo_bf  = (u16*)ws; ws += (size_t)2097152;
    u16* Qb     = (u16*)ws; ws += (size_t)8388608;
    u16* Qtb    = (u16*)ws; ws += (size_t)8388608;
    u16* ctxb   = (u16*)ws; ws += (size_t)8388608;
    float* xf   = (float*)ws;

    cvt3<<<6144, 256, 0, stream>>>(emb, Wq, Wo, emb_bf, Wq_bf, Wo_bf);
    gemm_q_kernel<<<dim3(8, 64), 256, 0, stream>>>(emb_bf, Wq_bf, bq, Qb, Qtb);
    attn_kernel<<<1024, 256, 0, stream>>>(Qb, Qtb, mask, probs, ctxb);
    gemm_o_kernel<<<dim3(8, 64), 256, 0, stream>>>(ctxb, Wo_bf, bo, emb, xf);
    ln_kernel<<<4096, 256, 0, stream>>>(xf, gamma, beta, out_ln);
}